// Round 1
// baseline (395.134 us; speedup 1.0000x reference)
//
#include <hip/hip_runtime.h>

// Problem constants (from reference)
#define N_NODES 12500
#define N_EDGES 200000
#define DIM 32          // IN == OUT == ATTN == 32
#define N_REL 200
#define N_BASES 50

#define OUT_ELEMS   (N_NODES * DIM)
#define ZERO_BLOCKS ((OUT_ELEMS + 1023) / 1024)   // 391

// Padded edge capacity: per-rel lists padded to multiples of 16.
// 200000 + 200*15 = 203000, round up to multiple of 64 for the edge grid.
#define PE_MAX 203008
#define INIT_BLOCKS ((PE_MAX + 1023) / 1024)      // 199

// ws layout (bytes):
//   [0, 409600)         bf16 relwT_bf[200][32][32]  TRANSPOSED: [r][o][i]
//   [409600, +8192)     bf16 aw_bf[32][128]         (= A_w, row-major)
//   [417792, +2048)     bf16 slwT_bf[32][32]        (= slw transposed [j][i])
//   [419840, +800)      int  counts[200]
//   [420640, +800)      int  cursors[200]
//   [421440, +800)      int  offsets[200]
//   [422240, +4*812032) int  spad/tpad/epad/rpad[PE_MAX]  (sorted-by-rel slots)
#define AWBF_OFF  (N_REL * 1024 * 2)
#define SLWT_OFF  (AWBF_OFF + 32 * 128 * 2)
#define CNT_OFF   (SLWT_OFF + 32 * 32 * 2)
#define CUR_OFF   (CNT_OFF + N_REL * 4)
#define OFF_OFF   (CUR_OFF + N_REL * 4)
#define SPAD_OFF  (OFF_OFF + N_REL * 4)
#define TPAD_OFF  (SPAD_OFF + PE_MAX * 4)
#define EPAD_OFF  (TPAD_OFF + PE_MAX * 4)
#define RPAD_OFF  (EPAD_OFF + PE_MAX * 4)

typedef __attribute__((ext_vector_type(8))) short short8;   // 8 bf16 (4 VGPRs)
typedef __attribute__((ext_vector_type(4))) float f32x4;    // MFMA acc

__device__ __forceinline__ unsigned short f2bf(float x) {
    union { float f; unsigned u; } v; v.f = x;
    unsigned r = (v.u + 0x7FFFu + ((v.u >> 16) & 1u)) >> 16;
    return (unsigned short)r;
}

__device__ __forceinline__ short8 cvt8(float4 a, float4 b) {
    short8 r;
    r[0] = (short)f2bf(a.x); r[1] = (short)f2bf(a.y);
    r[2] = (short)f2bf(a.z); r[3] = (short)f2bf(a.w);
    r[4] = (short)f2bf(b.x); r[5] = (short)f2bf(b.y);
    r[6] = (short)f2bf(b.z); r[7] = (short)f2bf(b.w);
    return r;
}

#define MFMA(A, B, C) __builtin_amdgcn_mfma_f32_16x16x32_bf16(A, B, C, 0, 0, 0)

// Prep: [0,200) rel_w basis combine (writes TRANSPOSED bf16 [r][o][i] so msg's
//   MFMA B-fragment is a contiguous short8); [200,591) zero out; 591 converts
//   Aw/slwT + zeroes counters; [592,791) inits the padded slot arrays
//   (tpad=-1 marks dummy slots; spad/epad=0 keeps gathers in-bounds).
__global__ __launch_bounds__(256) void prep_kernel(
    const float* __restrict__ weight,   // [50,32,32]
    const float* __restrict__ w_comp,   // [200,50]
    const float* __restrict__ Aw,       // [32,128]
    const float* __restrict__ slw,      // [32,32]
    unsigned short* __restrict__ relwT_bf,
    unsigned short* __restrict__ aw_bf,
    unsigned short* __restrict__ slwT_bf,
    int* __restrict__ counts,
    int* __restrict__ cursors,
    int* __restrict__ spad,
    int* __restrict__ tpad,
    int* __restrict__ epad,
    int* __restrict__ rpad,
    float* __restrict__ out)
{
    int b = blockIdx.x, tid = threadIdx.x;
    if (b < N_REL) {
        __shared__ float wc[N_BASES];
        if (tid < N_BASES) wc[tid] = w_comp[b * N_BASES + tid];
        __syncthreads();
        // float4-coalesced weight loads (R4: scalar version was latency-bound)
        const float* wp = weight + tid * 4;
        float4 acc = make_float4(0.f, 0.f, 0.f, 0.f);
        #pragma unroll 10
        for (int bb = 0; bb < N_BASES; bb++) {
            float4 w = *(const float4*)(wp + bb * 1024);
            float c = wc[bb];
            acc.x = fmaf(c, w.x, acc.x); acc.y = fmaf(c, w.y, acc.y);
            acc.z = fmaf(c, w.z, acc.z); acc.w = fmaf(c, w.w, acc.w);
        }
        // flat f = tid*4 + j over [i][o] (o fastest): i = tid>>3, o = (tid*4&31)+j
        // write transposed: relwT[r][o][i]
        int i  = tid >> 3;
        int o0 = (tid * 4) & 31;
        unsigned short* dst = relwT_bf + b * 1024 + i;
        dst[(o0 + 0) * 32] = f2bf(acc.x);
        dst[(o0 + 1) * 32] = f2bf(acc.y);
        dst[(o0 + 2) * 32] = f2bf(acc.z);
        dst[(o0 + 3) * 32] = f2bf(acc.w);
    } else if (b < N_REL + ZERO_BLOCKS) {
        int base = (b - N_REL) * 1024 + tid * 4;
        if (base + 3 < OUT_ELEMS)
            *(float4*)(out + base) = make_float4(0.f, 0.f, 0.f, 0.f);
        else
            for (int k = 0; k < 4; k++)
                if (base + k < OUT_ELEMS) out[base + k] = 0.f;
    } else if (b == N_REL + ZERO_BLOCKS) {
        for (int x = tid; x < 32 * 128; x += 256) aw_bf[x] = f2bf(Aw[x]);
        for (int x = tid; x < 32 * 32; x += 256) {
            int i = x >> 5, j = x & 31;          // slw[i][j]
            slwT_bf[j * 32 + i] = f2bf(slw[x]);
        }
        for (int x = tid; x < N_REL; x += 256) { counts[x] = 0; cursors[x] = 0; }
    } else {
        int base = (b - (N_REL + ZERO_BLOCKS + 1)) * 1024 + tid * 4;
        #pragma unroll
        for (int k = 0; k < 4; k++) {
            int j = base + k;
            if (j < PE_MAX) { spad[j] = 0; tpad[j] = -1; epad[j] = 0; rpad[j] = 0; }
        }
    }
}

// Counting sort by relation, step 1: histogram.
__global__ __launch_bounds__(256) void hist_kernel(
    const int* __restrict__ rel, int* __restrict__ counts)
{
    int e = blockIdx.x * 256 + threadIdx.x;
    if (e < N_EDGES) {
        int r = rel[e]; r = r < 0 ? 0 : (r >= N_REL ? N_REL - 1 : r);
        atomicAdd(&counts[r], 1);
    }
}

// Step 2: exclusive scan of per-rel counts padded to multiples of 16.
// 200 bins -> single tiny block; serial loop on thread 0 over LDS copies.
__global__ __launch_bounds__(256) void scan_kernel(
    const int* __restrict__ counts, int* __restrict__ offsets)
{
    __shared__ int c[N_REL];
    int tid = threadIdx.x;
    for (int x = tid; x < N_REL; x += 256) c[x] = counts[x];
    __syncthreads();
    if (tid == 0) {
        int run = 0;
        for (int r = 0; r < N_REL; r++) {
            offsets[r] = run;
            run += (c[r] + 15) & ~15;
        }
    }
}

// Step 3: scatter edges into relation-sorted padded slots. Within-rel order is
// nondeterministic (atomic cursor) — sum order only perturbs fp rounding.
__global__ __launch_bounds__(256) void scatter_kernel(
    const int* __restrict__ edge0, const int* __restrict__ edge1,
    const int* __restrict__ rel,
    const int* __restrict__ offsets, int* __restrict__ cursors,
    int* __restrict__ spad, int* __restrict__ tpad,
    int* __restrict__ epad, int* __restrict__ rpad)
{
    int e = blockIdx.x * 256 + threadIdx.x;
    if (e >= N_EDGES) return;
    int r = rel[e];   r = r < 0 ? 0 : (r >= N_REL   ? N_REL   - 1 : r);
    int s = edge0[e]; s = s < 0 ? 0 : (s >= N_NODES ? N_NODES - 1 : s);
    int t = edge1[e]; t = t < 0 ? 0 : (t >= N_NODES ? N_NODES - 1 : t);
    int pos = offsets[r] + atomicAdd(&cursors[r], 1);
    spad[pos] = s; tpad[pos] = t; epad[pos] = e; rpad[pos] = r;
}

// Edge kernel: one wave = 16 edges of ONE relation (guaranteed by padding),
// so ALL THREE products (h, cur, msg) are MFMAs. No LDS, no per-edge rel_w
// row streaming (2 KB/wave of relwT instead of 32 KB/wave), no bpermute loop.
// Dummy slots (tpad == -1) are computed but masked at the atomic.
__global__ __launch_bounds__(256) void edge_kernel(
    const float* __restrict__ node_feat,  // [N,32]
    const float* __restrict__ ttr,        // [E,32]
    const float* __restrict__ tre,        // [E,32]
    const float* __restrict__ Ab,         // [32]
    const float* __restrict__ Bw,         // [1,32]
    const float* __restrict__ Bb,         // [1]
    const int*  __restrict__ spad,        // [PE_MAX] src (rel-sorted)
    const int*  __restrict__ tpad,        // [PE_MAX] tgt, -1 = dummy
    const int*  __restrict__ epad,        // [PE_MAX] original edge id
    const int*  __restrict__ rpad,        // [PE_MAX] relation id
    const unsigned short* __restrict__ relwT_bf, // [200][32][32] bf16 (T)
    const unsigned short* __restrict__ aw_bf,    // [32][128] bf16
    const unsigned short* __restrict__ slwT_bf,  // [32][32]  bf16 (T)
    float* __restrict__ out)              // [N,32] fp32 (pre-zeroed)
{
    int tid  = threadIdx.x;
    int wave = tid >> 6;
    int lane = tid & 63;
    int m = lane & 15;          // edge row (A-frag) / out col n (B,C/D frag)
    int q = lane >> 4;          // quad: k-range / row-group
    int base = blockIdx.x * 64 + wave * 16;   // 3172*64 == PE_MAX exactly

    // lanes<16 load slot data; everyone else gets it via shfl
    int s_ld = 0, t_ld = -1, e_ld = 0;
    if (lane < 16) {
        s_ld = spad[base + lane];
        t_ld = tpad[base + lane];
        e_ld = epad[base + lane];
    }
    // wave-uniform relation: slot 0 of each 16-group is always a real edge
    // (padding is at the tail of each rel's region); beyond-total dummy waves
    // read the init value 0, harmless since their atomics are masked.
    int r_w = rpad[base];

    int s_m = __shfl(s_ld, m, 64);
    int t_m = __shfl(t_ld, m, 64);
    int e_m = __shfl(e_ld, m, 64);
    int t_mc = t_m < 0 ? 0 : t_m;

    // ---- gather A-operand data (lane holds edge m, k = 8q..8q+7) ----
    const float* sp = node_feat + s_m * DIM + q * 8;
    float4 sv0 = *(const float4*)sp, sv1 = *(const float4*)(sp + 4);
    const float* tp = node_feat + t_mc * DIM + q * 8;
    float4 tv0 = *(const float4*)tp, tv1 = *(const float4*)(tp + 4);
    const float* rp = tre + e_m * DIM + q * 8;
    float4 rv0 = *(const float4*)rp, rv1 = *(const float4*)(rp + 4);
    const float* qp = ttr + e_m * DIM + q * 8;
    float4 qv0 = *(const float4*)qp, qv1 = *(const float4*)(qp + 4);

    short8 fsrc = cvt8(sv0, sv1);
    short8 ftgt = cvt8(tv0, tv1);
    short8 fre  = cvt8(rv0, rv1);
    short8 ftr  = cvt8(qv0, qv1);

    // ---- B-operand fragments (lane: n = m, k = 8q..8q+7) ----
    short8 bA[4][2], bS[2], bM[2];
    #pragma unroll
    for (int hh = 0; hh < 2; hh++) {
        #pragma unroll
        for (int c = 0; c < 4; c++)
            bA[c][hh] = *(const short8*)(aw_bf + (16 * hh + m) * 128 + 32 * c + 8 * q);
        bS[hh] = *(const short8*)(slwT_bf + (16 * hh + m) * 32 + 8 * q);
        bM[hh] = *(const short8*)(relwT_bf + r_w * 1024 + (16 * hh + m) * 32 + 8 * q);
    }

    // ---- MFMAs: h = Ecat@Aw^T + Ab ; cur = tgt@slw ; msg = src@rel_w[r] ----
    float ab0 = Ab[m], ab1 = Ab[16 + m];
    f32x4 hacc0 = {ab0, ab0, ab0, ab0};
    f32x4 hacc1 = {ab1, ab1, ab1, ab1};
    f32x4 cacc0 = {0.f, 0.f, 0.f, 0.f};
    f32x4 cacc1 = {0.f, 0.f, 0.f, 0.f};
    f32x4 macc0 = {0.f, 0.f, 0.f, 0.f};
    f32x4 macc1 = {0.f, 0.f, 0.f, 0.f};

    hacc0 = MFMA(fsrc, bA[0][0], hacc0);  hacc1 = MFMA(fsrc, bA[0][1], hacc1);
    hacc0 = MFMA(ftgt, bA[1][0], hacc0);  hacc1 = MFMA(ftgt, bA[1][1], hacc1);
    hacc0 = MFMA(fre,  bA[2][0], hacc0);  hacc1 = MFMA(fre,  bA[2][1], hacc1);
    hacc0 = MFMA(ftr,  bA[3][0], hacc0);  hacc1 = MFMA(ftr,  bA[3][1], hacc1);
    cacc0 = MFMA(ftgt, bS[0], cacc0);     cacc1 = MFMA(ftgt, bS[1], cacc1);
    macc0 = MFMA(fsrc, bM[0], macc0);     macc1 = MFMA(fsrc, bM[1], macc1);

    // ---- epilogue: gate a = sigmoid(relu(h)@Bw + Bb), combine, scatter ----
    float bw0 = Bw[m], bw1 = Bw[16 + m], Bb0 = Bb[0];
    float av[4];
    #pragma unroll
    for (int v = 0; v < 4; v++) {
        float p = fmaxf(hacc0[v], 0.f) * bw0 + fmaxf(hacc1[v], 0.f) * bw1;
        p += __shfl_xor(p, 1, 16);
        p += __shfl_xor(p, 2, 16);
        p += __shfl_xor(p, 4, 16);
        p += __shfl_xor(p, 8, 16);
        av[v] = 1.f / (1.f + __expf(-(p + Bb0)));
    }
    #pragma unroll
    for (int v = 0; v < 4; v++) {
        int row = 4 * q + v;
        int tv = __shfl(t_ld, row, 64);
        if (tv >= 0) {
            atomicAdd(&out[tv * DIM + m],      cacc0[v] + macc0[v] * av[v]);
            atomicAdd(&out[tv * DIM + 16 + m], cacc1[v] + macc1[v] * av[v]);
        }
    }
}

extern "C" void kernel_launch(void* const* d_in, const int* in_sizes, int n_in,
                              void* d_out, int out_size, void* d_ws, size_t ws_size,
                              hipStream_t stream) {
    const float* node_feat = (const float*)d_in[0];
    const float* ttr       = (const float*)d_in[1];
    const float* tre       = (const float*)d_in[2];
    const float* weight    = (const float*)d_in[3];
    const float* w_comp    = (const float*)d_in[4];
    const float* slw       = (const float*)d_in[5];
    const float* Aw        = (const float*)d_in[6];
    const float* Ab        = (const float*)d_in[7];
    const float* Bw        = (const float*)d_in[8];
    const float* Bb        = (const float*)d_in[9];
    const int*  total_edge = (const int*)d_in[10];
    const int*  rel        = (const int*)d_in[11];
    const int*  edge0 = total_edge;
    const int*  edge1 = total_edge + N_EDGES;

    char* ws = (char*)d_ws;
    unsigned short* relwT_bf = (unsigned short*)ws;
    unsigned short* aw_bf    = (unsigned short*)(ws + AWBF_OFF);
    unsigned short* slwT_bf  = (unsigned short*)(ws + SLWT_OFF);
    int* counts  = (int*)(ws + CNT_OFF);
    int* cursors = (int*)(ws + CUR_OFF);
    int* offsets = (int*)(ws + OFF_OFF);
    int* spad    = (int*)(ws + SPAD_OFF);
    int* tpad    = (int*)(ws + TPAD_OFF);
    int* epad    = (int*)(ws + EPAD_OFF);
    int* rpad    = (int*)(ws + RPAD_OFF);
    float* out = (float*)d_out;

    prep_kernel<<<N_REL + ZERO_BLOCKS + 1 + INIT_BLOCKS, 256, 0, stream>>>(
        weight, w_comp, Aw, slw, relwT_bf, aw_bf, slwT_bf,
        counts, cursors, spad, tpad, epad, rpad, out);

    hist_kernel<<<(N_EDGES + 255) / 256, 256, 0, stream>>>(rel, counts);

    scan_kernel<<<1, 256, 0, stream>>>(counts, offsets);

    scatter_kernel<<<(N_EDGES + 255) / 256, 256, 0, stream>>>(
        edge0, edge1, rel, offsets, cursors, spad, tpad, epad, rpad);

    edge_kernel<<<PE_MAX / 64, 256, 0, stream>>>(
        node_feat, ttr, tre, Ab, Bw, Bb,
        spad, tpad, epad, rpad, relwT_bf, aw_bf, slwT_bf, out);
}

// Round 2
// 156.999 us; speedup vs baseline: 2.5168x; 2.5168x over previous
//
#include <hip/hip_runtime.h>

// Problem constants (from reference)
#define N_NODES 12500
#define N_EDGES 200000
#define DIM 32          // IN == OUT == ATTN == 32
#define N_REL 200
#define N_BASES 50

#define OUT_ELEMS   (N_NODES * DIM)
#define ZERO_BLOCKS ((OUT_ELEMS + 1023) / 1024)   // 391

// Padded edge capacity: per-rel lists padded to multiples of 16.
// 200000 + 200*15 = 203000, round up to multiple of 64 for the edge grid.
#define PE_MAX 203008
#define INIT_BLOCKS ((PE_MAX + 1023) / 1024)      // 199

// Counting-sort blocking: NB_BLK blocks each own a contiguous CHUNK of edges.
// Per-block LDS histograms + a [NB_BLK][N_REL] block-prefix table replace the
// R1 global-atomic cursors (162us: 200k device atomics over 200 addresses).
#define NB_BLK 100
#define CHUNK ((N_EDGES + NB_BLK - 1) / NB_BLK)   // 2000

// ws layout (bytes):
//   [0, 409600)         bf16 relwT_bf[200][32][32]  TRANSPOSED: [r][o][i]
//   [409600, +8192)     bf16 aw_bf[32][128]         (= A_w, row-major)
//   [417792, +2048)     bf16 slwT_bf[32][32]        (= slw transposed [j][i])
//   [419840, +80000)    int  blockCounts[NB_BLK][N_REL]
//   [499840, +80000)    int  blockBase[NB_BLK][N_REL]
//   [579840, +16*PE_MAX) int4 slot4[PE_MAX]  {src, tgt(-1=dummy), eid, rel}
#define AWBF_OFF  (N_REL * 1024 * 2)
#define SLWT_OFF  (AWBF_OFF + 32 * 128 * 2)
#define BC_OFF    (SLWT_OFF + 32 * 32 * 2)
#define BB_OFF    (BC_OFF + NB_BLK * N_REL * 4)
#define SLOT_OFF  (BB_OFF + NB_BLK * N_REL * 4)   // 579840, 16B-aligned

typedef __attribute__((ext_vector_type(8))) short short8;   // 8 bf16 (4 VGPRs)
typedef __attribute__((ext_vector_type(4))) float f32x4;    // MFMA acc

__device__ __forceinline__ unsigned short f2bf(float x) {
    union { float f; unsigned u; } v; v.f = x;
    unsigned r = (v.u + 0x7FFFu + ((v.u >> 16) & 1u)) >> 16;
    return (unsigned short)r;
}

__device__ __forceinline__ short8 cvt8(float4 a, float4 b) {
    short8 r;
    r[0] = (short)f2bf(a.x); r[1] = (short)f2bf(a.y);
    r[2] = (short)f2bf(a.z); r[3] = (short)f2bf(a.w);
    r[4] = (short)f2bf(b.x); r[5] = (short)f2bf(b.y);
    r[6] = (short)f2bf(b.z); r[7] = (short)f2bf(b.w);
    return r;
}

#define MFMA(A, B, C) __builtin_amdgcn_mfma_f32_16x16x32_bf16(A, B, C, 0, 0, 0)

// Prep: [0,200) rel_w basis combine; [200,591) zero out; 591 converts Aw/slwT;
//   [592,791) inits slot4 (tgt=-1 marks dummies, rel=0 keeps relw reads
//   in-bounds); [791,891) per-block LDS histogram -> blockCounts (NO atomics
//   to global; R1's scatter/hist global atomics on 200 addrs were the 162us).
__global__ __launch_bounds__(256) void prep_kernel(
    const float* __restrict__ weight,   // [50,32,32]
    const float* __restrict__ w_comp,   // [200,50]
    const float* __restrict__ Aw,       // [32,128]
    const float* __restrict__ slw,      // [32,32]
    const int*  __restrict__ rel,       // [E]
    unsigned short* __restrict__ relwT_bf,
    unsigned short* __restrict__ aw_bf,
    unsigned short* __restrict__ slwT_bf,
    int* __restrict__ blockCounts,
    int4* __restrict__ slot4,
    float* __restrict__ out)
{
    int b = blockIdx.x, tid = threadIdx.x;
    if (b < N_REL) {
        __shared__ float wc[N_BASES];
        if (tid < N_BASES) wc[tid] = w_comp[b * N_BASES + tid];
        __syncthreads();
        // float4-coalesced weight loads (R4: scalar version was latency-bound)
        const float* wp = weight + tid * 4;
        float4 acc = make_float4(0.f, 0.f, 0.f, 0.f);
        #pragma unroll 10
        for (int bb = 0; bb < N_BASES; bb++) {
            float4 w = *(const float4*)(wp + bb * 1024);
            float c = wc[bb];
            acc.x = fmaf(c, w.x, acc.x); acc.y = fmaf(c, w.y, acc.y);
            acc.z = fmaf(c, w.z, acc.z); acc.w = fmaf(c, w.w, acc.w);
        }
        // flat f = tid*4 + j over [i][o] (o fastest): i = tid>>3, o = (tid*4&31)+j
        // write transposed: relwT[r][o][i]
        int i  = tid >> 3;
        int o0 = (tid * 4) & 31;
        unsigned short* dst = relwT_bf + b * 1024 + i;
        dst[(o0 + 0) * 32] = f2bf(acc.x);
        dst[(o0 + 1) * 32] = f2bf(acc.y);
        dst[(o0 + 2) * 32] = f2bf(acc.z);
        dst[(o0 + 3) * 32] = f2bf(acc.w);
    } else if (b < N_REL + ZERO_BLOCKS) {
        int base = (b - N_REL) * 1024 + tid * 4;
        if (base + 3 < OUT_ELEMS)
            *(float4*)(out + base) = make_float4(0.f, 0.f, 0.f, 0.f);
        else
            for (int k = 0; k < 4; k++)
                if (base + k < OUT_ELEMS) out[base + k] = 0.f;
    } else if (b == N_REL + ZERO_BLOCKS) {
        for (int x = tid; x < 32 * 128; x += 256) aw_bf[x] = f2bf(Aw[x]);
        for (int x = tid; x < 32 * 32; x += 256) {
            int i = x >> 5, j = x & 31;          // slw[i][j]
            slwT_bf[j * 32 + i] = f2bf(slw[x]);
        }
    } else if (b < N_REL + ZERO_BLOCKS + 1 + INIT_BLOCKS) {
        int base = (b - (N_REL + ZERO_BLOCKS + 1)) * 1024 + tid * 4;
        #pragma unroll
        for (int k = 0; k < 4; k++) {
            int j = base + k;
            if (j < PE_MAX) slot4[j] = make_int4(0, -1, 0, 0);
        }
    } else {
        // per-block histogram: LDS atomics only, plain stores to blockCounts
        __shared__ int h[N_REL];
        int blk = b - (N_REL + ZERO_BLOCKS + 1 + INIT_BLOCKS);
        for (int x = tid; x < N_REL; x += 256) h[x] = 0;
        __syncthreads();
        int e0 = blk * CHUNK;
        int e1 = e0 + CHUNK; if (e1 > N_EDGES) e1 = N_EDGES;
        for (int e = e0 + tid; e < e1; e += 256) {
            int r = rel[e]; r = r < 0 ? 0 : (r >= N_REL ? N_REL - 1 : r);
            atomicAdd(&h[r], 1);
        }
        __syncthreads();
        for (int x = tid; x < N_REL; x += 256)
            blockCounts[blk * N_REL + x] = h[x];
    }
}

// Scan: one block. Thread r (<200) owns bin r: total over blocks, then a
// serial 16-padded exclusive scan over bins on thread 0, then per-block
// bases blockBase[blk][r] = off[r] + prefix(blockCounts[<blk][r]).
__global__ __launch_bounds__(256) void scan_kernel(
    const int* __restrict__ blockCounts, int* __restrict__ blockBase)
{
    __shared__ int tot[N_REL];
    __shared__ int off[N_REL];
    int tid = threadIdx.x;
    if (tid < N_REL) {
        int run = 0;
        for (int b = 0; b < NB_BLK; b++) run += blockCounts[b * N_REL + tid];
        tot[tid] = run;
    }
    __syncthreads();
    if (tid == 0) {
        int run = 0;
        for (int r = 0; r < N_REL; r++) {
            off[r] = run;
            run += (tot[r] + 15) & ~15;
        }
    }
    __syncthreads();
    if (tid < N_REL) {
        int run = off[tid];
        for (int b = 0; b < NB_BLK; b++) {
            blockBase[b * N_REL + tid] = run;
            run += blockCounts[b * N_REL + tid];
        }
    }
}

// Scatter: block blk claims positions from LDS cursors seeded with
// blockBase[blk][*]; one packed int4 store per edge. No global atomics.
// Within-rel order is nondeterministic (LDS atomic) — fp rounding only.
__global__ __launch_bounds__(256) void scatter_kernel(
    const int* __restrict__ edge0, const int* __restrict__ edge1,
    const int* __restrict__ rel,
    const int* __restrict__ blockBase,
    int4* __restrict__ slot4)
{
    __shared__ int cur[N_REL];
    int blk = blockIdx.x, tid = threadIdx.x;
    for (int x = tid; x < N_REL; x += 256) cur[x] = blockBase[blk * N_REL + x];
    __syncthreads();
    int e0 = blk * CHUNK;
    int e1 = e0 + CHUNK; if (e1 > N_EDGES) e1 = N_EDGES;
    for (int e = e0 + tid; e < e1; e += 256) {
        int r = rel[e];   r = r < 0 ? 0 : (r >= N_REL   ? N_REL   - 1 : r);
        int s = edge0[e]; s = s < 0 ? 0 : (s >= N_NODES ? N_NODES - 1 : s);
        int t = edge1[e]; t = t < 0 ? 0 : (t >= N_NODES ? N_NODES - 1 : t);
        int pos = atomicAdd(&cur[r], 1);
        slot4[pos] = make_int4(s, t, e, r);
    }
}

// Edge kernel: one wave = 16 edges of ONE relation (guaranteed by padding),
// so ALL THREE products (h, cur, msg) are MFMAs. No LDS, no per-edge rel_w
// row streaming, no bpermute loop. Dummy slots (tgt == -1) masked at the atomic.
__global__ __launch_bounds__(256) void edge_kernel(
    const float* __restrict__ node_feat,  // [N,32]
    const float* __restrict__ ttr,        // [E,32]
    const float* __restrict__ tre,        // [E,32]
    const float* __restrict__ Ab,         // [32]
    const float* __restrict__ Bw,         // [1,32]
    const float* __restrict__ Bb,         // [1]
    const int4* __restrict__ slot4,       // [PE_MAX] {s, t(-1=dummy), e, r}
    const unsigned short* __restrict__ relwT_bf, // [200][32][32] bf16 (T)
    const unsigned short* __restrict__ aw_bf,    // [32][128] bf16
    const unsigned short* __restrict__ slwT_bf,  // [32][32]  bf16 (T)
    float* __restrict__ out)              // [N,32] fp32 (pre-zeroed)
{
    int tid  = threadIdx.x;
    int wave = tid >> 6;
    int lane = tid & 63;
    int m = lane & 15;          // edge row (A-frag) / out col n (B,C/D frag)
    int q = lane >> 4;          // quad: k-range / row-group
    int base = blockIdx.x * 64 + wave * 16;   // 3172*64 == PE_MAX exactly

    // lanes<16 load slot data (one coalesced 256B int4 burst); shfl the rest
    int s_ld = 0, t_ld = -1, e_ld = 0, r_ld = 0;
    if (lane < 16) {
        int4 v = slot4[base + lane];
        s_ld = v.x; t_ld = v.y; e_ld = v.z; r_ld = v.w;
    }
    // wave-uniform relation: slot 0 of each 16-group is real whenever the
    // group exists (padding sits at each rel's tail); fully-dummy tail groups
    // read the init value r=0, harmless since their atomics are masked.
    int r_w = __shfl(r_ld, 0, 64);

    int s_m = __shfl(s_ld, m, 64);
    int t_m = __shfl(t_ld, m, 64);
    int e_m = __shfl(e_ld, m, 64);
    int t_mc = t_m < 0 ? 0 : t_m;

    // ---- gather A-operand data (lane holds edge m, k = 8q..8q+7) ----
    const float* sp = node_feat + s_m * DIM + q * 8;
    float4 sv0 = *(const float4*)sp, sv1 = *(const float4*)(sp + 4);
    const float* tp = node_feat + t_mc * DIM + q * 8;
    float4 tv0 = *(const float4*)tp, tv1 = *(const float4*)(tp + 4);
    const float* rp = tre + e_m * DIM + q * 8;
    float4 rv0 = *(const float4*)rp, rv1 = *(const float4*)(rp + 4);
    const float* qp = ttr + e_m * DIM + q * 8;
    float4 qv0 = *(const float4*)qp, qv1 = *(const float4*)(qp + 4);

    short8 fsrc = cvt8(sv0, sv1);
    short8 ftgt = cvt8(tv0, tv1);
    short8 fre  = cvt8(rv0, rv1);
    short8 ftr  = cvt8(qv0, qv1);

    // ---- B-operand fragments (lane: n = m, k = 8q..8q+7) ----
    short8 bA[4][2], bS[2], bM[2];
    #pragma unroll
    for (int hh = 0; hh < 2; hh++) {
        #pragma unroll
        for (int c = 0; c < 4; c++)
            bA[c][hh] = *(const short8*)(aw_bf + (16 * hh + m) * 128 + 32 * c + 8 * q);
        bS[hh] = *(const short8*)(slwT_bf + (16 * hh + m) * 32 + 8 * q);
        bM[hh] = *(const short8*)(relwT_bf + r_w * 1024 + (16 * hh + m) * 32 + 8 * q);
    }

    // ---- MFMAs: h = Ecat@Aw^T + Ab ; cur = tgt@slw ; msg = src@rel_w[r] ----
    float ab0 = Ab[m], ab1 = Ab[16 + m];
    f32x4 hacc0 = {ab0, ab0, ab0, ab0};
    f32x4 hacc1 = {ab1, ab1, ab1, ab1};
    f32x4 cacc0 = {0.f, 0.f, 0.f, 0.f};
    f32x4 cacc1 = {0.f, 0.f, 0.f, 0.f};
    f32x4 macc0 = {0.f, 0.f, 0.f, 0.f};
    f32x4 macc1 = {0.f, 0.f, 0.f, 0.f};

    hacc0 = MFMA(fsrc, bA[0][0], hacc0);  hacc1 = MFMA(fsrc, bA[0][1], hacc1);
    hacc0 = MFMA(ftgt, bA[1][0], hacc0);  hacc1 = MFMA(ftgt, bA[1][1], hacc1);
    hacc0 = MFMA(fre,  bA[2][0], hacc0);  hacc1 = MFMA(fre,  bA[2][1], hacc1);
    hacc0 = MFMA(ftr,  bA[3][0], hacc0);  hacc1 = MFMA(ftr,  bA[3][1], hacc1);
    cacc0 = MFMA(ftgt, bS[0], cacc0);     cacc1 = MFMA(ftgt, bS[1], cacc1);
    macc0 = MFMA(fsrc, bM[0], macc0);     macc1 = MFMA(fsrc, bM[1], macc1);

    // ---- epilogue: gate a = sigmoid(relu(h)@Bw + Bb), combine, scatter ----
    float bw0 = Bw[m], bw1 = Bw[16 + m], Bb0 = Bb[0];
    float av[4];
    #pragma unroll
    for (int v = 0; v < 4; v++) {
        float p = fmaxf(hacc0[v], 0.f) * bw0 + fmaxf(hacc1[v], 0.f) * bw1;
        p += __shfl_xor(p, 1, 16);
        p += __shfl_xor(p, 2, 16);
        p += __shfl_xor(p, 4, 16);
        p += __shfl_xor(p, 8, 16);
        av[v] = 1.f / (1.f + __expf(-(p + Bb0)));
    }
    #pragma unroll
    for (int v = 0; v < 4; v++) {
        int row = 4 * q + v;
        int tv = __shfl(t_ld, row, 64);
        if (tv >= 0) {
            atomicAdd(&out[tv * DIM + m],      cacc0[v] + macc0[v] * av[v]);
            atomicAdd(&out[tv * DIM + 16 + m], cacc1[v] + macc1[v] * av[v]);
        }
    }
}

extern "C" void kernel_launch(void* const* d_in, const int* in_sizes, int n_in,
                              void* d_out, int out_size, void* d_ws, size_t ws_size,
                              hipStream_t stream) {
    const float* node_feat = (const float*)d_in[0];
    const float* ttr       = (const float*)d_in[1];
    const float* tre       = (const float*)d_in[2];
    const float* weight    = (const float*)d_in[3];
    const float* w_comp    = (const float*)d_in[4];
    const float* slw       = (const float*)d_in[5];
    const float* Aw        = (const float*)d_in[6];
    const float* Ab        = (const float*)d_in[7];
    const float* Bw        = (const float*)d_in[8];
    const float* Bb        = (const float*)d_in[9];
    const int*  total_edge = (const int*)d_in[10];
    const int*  rel        = (const int*)d_in[11];
    const int*  edge0 = total_edge;
    const int*  edge1 = total_edge + N_EDGES;

    char* ws = (char*)d_ws;
    unsigned short* relwT_bf = (unsigned short*)ws;
    unsigned short* aw_bf    = (unsigned short*)(ws + AWBF_OFF);
    unsigned short* slwT_bf  = (unsigned short*)(ws + SLWT_OFF);
    int*  blockCounts = (int*)(ws + BC_OFF);
    int*  blockBase   = (int*)(ws + BB_OFF);
    int4* slot4       = (int4*)(ws + SLOT_OFF);
    float* out = (float*)d_out;

    prep_kernel<<<N_REL + ZERO_BLOCKS + 1 + INIT_BLOCKS + NB_BLK, 256, 0, stream>>>(
        weight, w_comp, Aw, slw, rel, relwT_bf, aw_bf, slwT_bf,
        blockCounts, slot4, out);

    scan_kernel<<<1, 256, 0, stream>>>(blockCounts, blockBase);

    scatter_kernel<<<NB_BLK, 256, 0, stream>>>(
        edge0, edge1, rel, blockBase, slot4);

    edge_kernel<<<PE_MAX / 64, 256, 0, stream>>>(
        node_feat, ttr, tre, Ab, Bw, Bb,
        slot4, relwT_bf, aw_bf, slwT_bf, out);
}